// Round 17
// baseline (57.272 us; speedup 1.0000x reference)
//
#include <hip/hip_runtime.h>
#include <cstddef>
#include <cstdint>

// Problem constants
#define Bb   32
#define Ss   512
#define Dd   768
#define Ww   256
#define Pp   1024
#define NH   300            // hidden
#define SLOT1 320           // slot-1 column base (128B-aligned)
#define NPAD 640            // padded proj row: [0,300) slot0, [320,620) slot1
#define Mm   (Bb * Ww)      // 8192 words
#define ZROW 8192           // zero row index in each proj buffer
#define ZOFF (ZROW * NPAD)  // element offset of zero row
#define PBUF ((Mm + 1) * NPAD)   // elements per proj partial buffer (8193 rows)
#define KH   384            // K half
#define NST  6              // K-steps per block (KH/64)

typedef __attribute__((ext_vector_type(8))) short bf16x8;
typedef __attribute__((ext_vector_type(4))) float f32x4;

#define GPTR(p) ((const __attribute__((address_space(1))) void*)(p))
#define LPTR(p) ((__attribute__((address_space(3))) void*)(p))

__device__ __forceinline__ unsigned short f2bf(float x) {
    unsigned u = __builtin_bit_cast(unsigned, x);
    u += 0x7fffu + ((u >> 16) & 1u);          // RNE
    return (unsigned short)(u >> 16);
}
__device__ __forceinline__ float bf2f(unsigned short u) {
    return __builtin_bit_cast(float, (unsigned)u << 16);
}
__device__ __forceinline__ float fast_tanh(float x) {
    x = fminf(fmaxf(x, -15.0f), 15.0f);
    float e = __expf(2.0f * x);
    return 1.0f - 2.0f * __builtin_amdgcn_rcpf(e + 1.0f);
}

// -------------------------------------------------------------------------
// Kernel 1 (prep), grid-stride 1024x256:
//   (a) mean-pool h -> emb bf16  (b) repack w1 -> BmatT  (c) zero rows
// -------------------------------------------------------------------------
__global__ __launch_bounds__(256) void prep_kernel(
    const float* __restrict__ h, const float* __restrict__ w1,
    const int* __restrict__ word_start, const int* __restrict__ word_len,
    unsigned short* __restrict__ emb, unsigned short* __restrict__ bmatT,
    unsigned short* __restrict__ proj)
{
    const int gid    = blockIdx.x * 256 + threadIdx.x;
    const int stride = 1024 * 256;

    for (int u = gid; u < Mm * 192; u += stride) {
        const int m = u / 192;
        const int c = u - m * 192;
        const int b   = m >> 8;
        const int s0  = word_start[m];
        const int len = word_len[m];
        const float* p = h + (size_t)b * (Ss * Dd) + (size_t)s0 * Dd + c * 4;
        float4 v = *(const float4*)p;
        if (len == 2) {
            float4 v2 = *(const float4*)(p + Dd);
            v.x = (v.x + v2.x) * 0.5f;
            v.y = (v.y + v2.y) * 0.5f;
            v.z = (v.z + v2.z) * 0.5f;
            v.w = (v.w + v2.w) * 0.5f;
        }
        ushort4 o = make_ushort4(f2bf(v.x), f2bf(v.y), f2bf(v.z), f2bf(v.w));
        *(ushort4*)(emb + (size_t)m * Dd + c * 4) = o;
    }

    for (int u = gid; u < Dd * NPAD; u += stride) {
        const int k = u / NPAD;
        const int n = u - k * NPAD;
        float v = 0.0f;
        if (n < NH)                            v = w1[(size_t)k * NH + n];
        else if (n >= SLOT1 && n < SLOT1 + NH) v = w1[(size_t)(Dd + k) * NH + (n - SLOT1)];
        bmatT[(size_t)n * Dd + k] = f2bf(v);
    }

    if (gid < NPAD / 4) {
        *(ushort4*)(proj + ZOFF + gid * 4)        = make_ushort4(0, 0, 0, 0);
        *(ushort4*)(proj + PBUF + ZOFF + gid * 4) = make_ushort4(0, 0, 0, 0);
    }
}

// -------------------------------------------------------------------------
// Kernel 2: MFMA bf16 GEMM, K-SPLIT x2, BK=64, COUNTED-VMCNT (T4):
// 640 blocks. Tile 128x128, 6 K-steps of 32 MFMA/wave (vs 12x16 in R16 —
// halves the per-step fixed-latency count, doubles per-step compute cover).
// Triple-buffered LDS 96 KB (1 block/CU: occupancy measured non-binding,
// R14/R15). Per step: wait vmcnt(8) (step-k's 8 loads done, k+1's 8 in
// flight) -> s_barrier -> COMPUTE(k) -> STAGE(k+2). Never drained mid-loop.
// Race-proof: STAGE(k+2) targets buf (k+2)%3 = (k-1)%3, last read in
// COMPUTE(k-1), which all waves finished before this step's barrier.
// Bijective XCD swizzle (640 = 8*80), kh-major.
// -------------------------------------------------------------------------
__global__ __launch_bounds__(256, 1) void gemm_kernel(
    const unsigned short* __restrict__ emb, const unsigned short* __restrict__ bmatT,
    unsigned short* __restrict__ proj)
{
    __shared__ bf16x8 Al[3][8][128];   // 48 KB: [buf][kb 0..7][row]
    __shared__ bf16x8 Bl[3][8][128];   // 48 KB

    const int bid = blockIdx.x;
    const int t   = threadIdx.x;

    const int swz   = (bid & 7) * 80 + (bid >> 3);
    const int kh    = swz / 320;            // 0,1
    const int tIdx  = swz - kh * 320;
    const int mBase = (tIdx / 5) * 128;
    const int nBase = (tIdx % 5) * 128;
    const int kOff  = kh * KH;

    // staging roles: row = t&127, base k-oct = t>>7; 4 chunks per operand,
    // chunk j -> kb = (t>>7) + 2j, src k-elem offset ((t>>7)+2j)*8
    const int srow = t & 127;
    const int skb8 = (t >> 7) << 3;
    const unsigned short* srcA = emb   + (size_t)(mBase + srow) * Dd + kOff + skb8;
    const unsigned short* srcB = bmatT + (size_t)(nBase + srow) * Dd + kOff + skb8;
    char* ldsA = (char*)&Al[0][0][0] + t * 16;
    char* ldsB = (char*)&Bl[0][0][0] + t * 16;

    // compute roles
    const int lane = t & 63;
    const int w    = t >> 6;
    const int wr   = w >> 1;
    const int wc   = w & 1;
    const int fr   = lane & 15;
    const int kb   = lane >> 4;

    f32x4 acc[4][4];
#pragma unroll
    for (int i = 0; i < 4; ++i)
#pragma unroll
        for (int j = 0; j < 4; ++j)
#pragma unroll
            for (int r = 0; r < 4; ++r) acc[i][j][r] = 0.0f;

// 8 loads per STAGE (4 A + 4 B); buf stride 16384 B; chunk j at +j*4096
#define STAGE(c, off)                                                                          \
    _Pragma("unroll")                                                                          \
    for (int j = 0; j < 4; ++j) {                                                              \
        __builtin_amdgcn_global_load_lds(GPTR(srcA + (off) + j * 16),                          \
                                         LPTR(ldsA + (c) * 16384 + j * 4096), 16, 0, 0);       \
        __builtin_amdgcn_global_load_lds(GPTR(srcB + (off) + j * 16),                          \
                                         LPTR(ldsB + (c) * 16384 + j * 4096), 16, 0, 0);       \
    }

// 32 MFMA per wave per step: kb-groups kb and kb+4
#define COMPUTE(c)                                                                             \
    {                                                                                          \
        _Pragma("unroll")                                                                      \
        for (int g = 0; g < 2; ++g) {                                                          \
            const int kbg = kb + g * 4;                                                        \
            bf16x8 a[4], b[4];                                                                 \
            _Pragma("unroll")                                                                  \
            for (int mi = 0; mi < 4; ++mi) a[mi] = Al[c][kbg][wr * 64 + mi * 16 + fr];         \
            _Pragma("unroll")                                                                  \
            for (int ni = 0; ni < 4; ++ni) b[ni] = Bl[c][kbg][wc * 64 + ni * 16 + fr];         \
            _Pragma("unroll")                                                                  \
            for (int mi = 0; mi < 4; ++mi)                                                     \
                _Pragma("unroll")                                                              \
                for (int ni = 0; ni < 4; ++ni)                                                 \
                    acc[mi][ni] = __builtin_amdgcn_mfma_f32_16x16x32_bf16(a[mi], b[ni],        \
                                                                          acc[mi][ni], 0, 0, 0); \
        }                                                                                      \
    }

#define KSTEP(k, cnt)                                                     \
    asm volatile("s_waitcnt vmcnt(" #cnt ")" ::: "memory");               \
    __builtin_amdgcn_sched_barrier(0);                                    \
    __builtin_amdgcn_s_barrier();                                         \
    asm volatile("" ::: "memory");                                        \
    __builtin_amdgcn_sched_barrier(0);                                    \
    COMPUTE((k) % 3);                                                     \
    if ((k) < NST - 2) { STAGE((k + 2) % 3, (k + 2) * 64); }

    // prologue: steps 0 and 1 in flight (8 loads each)
    STAGE(0, 0);
    STAGE(1, 64);

    KSTEP(0, 8)  KSTEP(1, 8)  KSTEP(2, 8)
    KSTEP(3, 8)  KSTEP(4, 8)  KSTEP(5, 0)

#undef KSTEP
#undef STAGE
#undef COMPUTE

    // C/D layout: col = lane&15, row = (lane>>4)*4 + r   [verified m89/m91]
    unsigned short* projh = proj + (size_t)kh * PBUF;
    const int r0 = mBase + wr * 64 + kb * 4;
    const int c0 = nBase + wc * 64 + fr;
#pragma unroll
    for (int mi = 0; mi < 4; ++mi)
#pragma unroll
        for (int ni = 0; ni < 4; ++ni)
#pragma unroll
            for (int r = 0; r < 4; ++r)
                projh[(size_t)(r0 + mi * 16 + r) * NPAD + c0 + ni * 16] = f2bf(acc[mi][ni][r]);
}

// -------------------------------------------------------------------------
// Kernel 3: 4 pairs per wave; gathers BOTH K-partials (summed before tanh);
// LDS-tree reduce + wave-parallel softmax. (R13-identical.)
// -------------------------------------------------------------------------
__global__ __launch_bounds__(256) void mlp_kernel(
    const unsigned short* __restrict__ proj,
    const float* __restrict__ b1, const float* __restrict__ w2,
    const float* __restrict__ b2, const int* __restrict__ pair_idx,
    float* __restrict__ out)
{
    __shared__ float red[4][64][17];   // [wave][src lane][16 outputs + pad]

    const int wv   = threadIdx.x >> 6;
    const int wave = blockIdx.x * 4 + wv;                   // 0..8191
    const int lane = threadIdx.x & 63;
    const int wid0 = wave * 4;                              // 4 pairs, same batch
    const int b    = wid0 >> 10;
    const int rbase = b * Ww * NPAD;
    const unsigned short* proj1 = proj + PBUF;

    const int4 piA = *(const int4*)(pair_idx + wid0 * 2);
    const int4 piB = *(const int4*)(pair_idx + wid0 * 2 + 4);
    const int idx[8] = {piA.x, piA.y, piA.z, piA.w, piB.x, piB.y, piB.z, piB.w};

    int off0[4], off1[4];
#pragma unroll
    for (int p = 0; p < 4; ++p) {
        const int i0 = idx[p * 2], i1 = idx[p * 2 + 1];
        off0[p] = (i0 >= 0) ? rbase + i0 * NPAD : ZOFF;
        off1[p] = ((i1 >= 0) ? rbase + i1 * NPAD : ZOFF) + SLOT1;
    }

    unsigned short g0a[4][5], g0b[4][5], g1a[4][5], g1b[4][5];
#pragma unroll
    for (int p = 0; p < 4; ++p)
#pragma unroll
        for (int it = 0; it < 5; ++it) {
            const int j = lane + it * 64;     // j<320; cols [300,320) are zero
            g0a[p][it] = proj [(size_t)off0[p] + j];
            g0b[p][it] = proj1[(size_t)off0[p] + j];
            g1a[p][it] = proj [(size_t)off1[p] + j];
            g1b[p][it] = proj1[(size_t)off1[p] + j];
        }

    float acc[4][4];
#pragma unroll
    for (int p = 0; p < 4; ++p)
#pragma unroll
        for (int c = 0; c < 4; ++c) acc[p][c] = 0.0f;

#pragma unroll
    for (int it = 0; it < 5; ++it) {
        const int j  = lane + it * 64;
        const bool ok = (j < NH);
        const float bj = ok ? b1[j] : 0.0f;
        float4 wv4 = make_float4(0.f, 0.f, 0.f, 0.f);
        if (ok) wv4 = *(const float4*)(w2 + (size_t)j * 4);
#pragma unroll
        for (int p = 0; p < 4; ++p) {
            const float v = bj + (bf2f(g0a[p][it]) + bf2f(g0b[p][it]))
                               + (bf2f(g1a[p][it]) + bf2f(g1b[p][it]));
            const float x = ok ? fast_tanh(v) : 0.0f;
            acc[p][0] = fmaf(x, wv4.x, acc[p][0]);
            acc[p][1] = fmaf(x, wv4.y, acc[p][1]);
            acc[p][2] = fmaf(x, wv4.z, acc[p][2]);
            acc[p][3] = fmaf(x, wv4.w, acc[p][3]);
        }
    }

#pragma unroll
    for (int p = 0; p < 4; ++p)
#pragma unroll
        for (int c = 0; c < 4; ++c)
            red[wv][lane][p * 4 + c] = acc[p][c];
    __syncthreads();

    const int o = lane >> 2;          // output id = p*4+c
    const int g = lane & 3;           // source quarter
    float v = 0.0f;
#pragma unroll
    for (int i = 0; i < 16; ++i)
        v += red[wv][g * 16 + i][o];
    v += __shfl_xor(v, 1, 64);
    v += __shfl_xor(v, 2, 64);

    const int c = o & 3;
    const float l = v + b2[c];
    float mx = fmaxf(l, __shfl_xor(l, 4, 64));
    mx = fmaxf(mx, __shfl_xor(mx, 8, 64));
    const float e = __expf(l - mx);
    float s = e + __shfl_xor(e, 4, 64);
    s += __shfl_xor(s, 8, 64);
    const float r = e * __builtin_amdgcn_rcpf(s);
    if (g == 0)
        out[(size_t)(wid0 + (o >> 2)) * 4 + c] = r;
}

// -------------------------------------------------------------------------
extern "C" void kernel_launch(void* const* d_in, const int* in_sizes, int n_in,
                              void* d_out, int out_size, void* d_ws, size_t ws_size,
                              hipStream_t stream)
{
    const float* h          = (const float*)d_in[0];
    const float* w1         = (const float*)d_in[1];
    const float* b1         = (const float*)d_in[2];
    const float* w2         = (const float*)d_in[3];
    const float* b2         = (const float*)d_in[4];
    const int*   word_start = (const int*)d_in[5];
    const int*   word_len   = (const int*)d_in[6];
    const int*   pair_idx   = (const int*)d_in[7];
    float*       out        = (float*)d_out;

    // workspace layout (all bf16)
    unsigned short* proj  = (unsigned short*)d_ws;                       // 2 partial bufs = 20,974,080 B
    unsigned short* emb   = (unsigned short*)((char*)d_ws + 20975616);   // 12,582,912 B
    unsigned short* bmatT = (unsigned short*)((char*)d_ws + 33558528);   // 983,040 B

    prep_kernel<<<dim3(1024), dim3(256), 0, stream>>>(
        h, w1, word_start, word_len, emb, bmatT, proj);
    gemm_kernel<<<dim3(640),  dim3(256), 0, stream>>>(emb, bmatT, proj);
    mlp_kernel <<<dim3(2048), dim3(256), 0, stream>>>(proj, b1, w2, b2, pair_idx, out);
}